// Round 1
// baseline (551.411 us; speedup 1.0000x reference)
//
#include <hip/hip_runtime.h>
#include <cstdint>

#define NT 8192
#define DD 1024
#define NE 8

typedef __attribute__((ext_vector_type(8))) _Float16 half8;
typedef __attribute__((ext_vector_type(4))) float f32x4;

__device__ __forceinline__ unsigned short f2h_bits(float f) {
  _Float16 h = (_Float16)f;
  return __builtin_bit_cast(unsigned short, h);
}

// async global->LDS, 16B per lane. LDS dest must be wave-uniform base + lane*16.
#define GLDS16(gp, lp) __builtin_amdgcn_global_load_lds( \
  (__attribute__((address_space(1))) void*)(uintptr_t)(gp), \
  (__attribute__((address_space(3))) void*)(uintptr_t)(lp), 16, 0, 0)

// ---------------- zero counts ----------------
__global__ void zero_kernel(int* counts) {
  if (threadIdx.x < NE) counts[threadIdx.x] = 0;
}

// ---------------- weight cast+transpose: fp32 [e][k][n] -> fp16 [e][n][k] ----------------
__global__ __launch_bounds__(256) void wcast_kernel(
    const float* __restrict__ W1, const float* __restrict__ W2,
    _Float16* __restrict__ W1t, _Float16* __restrict__ W2t) {
  __shared__ float tile[64][65];
  const int z = blockIdx.z;                // 0..15: [0,8)=W1, [8,16)=W2
  const float* W = (z < 8 ? W1 : W2) + (size_t)(z & 7) * (DD * DD);
  _Float16* Wt   = (z < 8 ? W1t : W2t) + (size_t)(z & 7) * (DD * DD);
  const int k0 = blockIdx.x * 64, n0 = blockIdx.y * 64;
  const int tid = threadIdx.x;
#pragma unroll
  for (int it = 0; it < 4; ++it) {
    int idx = it * 256 + tid;              // 0..1023
    int r = idx >> 4;                      // k-row 0..63
    int q = idx & 15;                      // float4 col
    float4 v = *(const float4*)(W + (size_t)(k0 + r) * DD + n0 + q * 4);
    tile[r][q * 4 + 0] = v.x; tile[r][q * 4 + 1] = v.y;
    tile[r][q * 4 + 2] = v.z; tile[r][q * 4 + 3] = v.w;
  }
  __syncthreads();
#pragma unroll
  for (int it = 0; it < 4; ++it) {
    int idx = it * 256 + tid;
    int n = idx >> 4;                      // out row (n) 0..63
    int q = idx & 15;                      // k 4-chunk
    ushort4 o;
    o.x = f2h_bits(tile[q * 4 + 0][n]);
    o.y = f2h_bits(tile[q * 4 + 1][n]);
    o.z = f2h_bits(tile[q * 4 + 2][n]);
    o.w = f2h_bits(tile[q * 4 + 3][n]);
    *(ushort4*)(Wt + (size_t)(n0 + n) * DD + k0 + q * 4) = o;
  }
}

// ---------------- gating: fp32 logits, softmax, argmax ----------------
__global__ __launch_bounds__(256) void gate_kernel(
    const float* __restrict__ x, const float* __restrict__ Wg, const float* __restrict__ bg,
    int* __restrict__ assign, float* __restrict__ wgt, int* __restrict__ counts) {
  const int t = blockIdx.x;
  const int tid = threadIdx.x;
  float4 xv = ((const float4*)(x + (size_t)t * DD))[tid];
  float xa[4] = {xv.x, xv.y, xv.z, xv.w};
  float p[NE];
#pragma unroll
  for (int e = 0; e < NE; ++e) p[e] = 0.f;
  const float* wr = Wg + (size_t)tid * 4 * NE;   // rows tid*4 .. +3
#pragma unroll
  for (int j = 0; j < 4; ++j) {
    float xs = xa[j];
#pragma unroll
    for (int e = 0; e < NE; ++e) p[e] += xs * wr[j * NE + e];
  }
  // wave reduce (64 lanes)
#pragma unroll
  for (int e = 0; e < NE; ++e) {
    float v = p[e];
    for (int off = 32; off > 0; off >>= 1) v += __shfl_down(v, off, 64);
    p[e] = v;
  }
  __shared__ float red[4][NE];
  int lane = tid & 63, w = tid >> 6;
  if (lane == 0) {
#pragma unroll
    for (int e = 0; e < NE; ++e) red[w][e] = p[e];
  }
  __syncthreads();
  if (tid == 0) {
    float l[NE];
#pragma unroll
    for (int e = 0; e < NE; ++e) l[e] = red[0][e] + red[1][e] + red[2][e] + red[3][e] + bg[e];
    int a = 0; float best = l[0];
#pragma unroll
    for (int e = 1; e < NE; ++e) if (l[e] > best) { best = l[e]; a = e; }
    float s = 0.f;
#pragma unroll
    for (int e = 0; e < NE; ++e) s += expf(l[e] - best);
    assign[t] = a;
    wgt[t] = 1.0f / s;                     // = softmax prob of argmax expert
    atomicAdd(&counts[a], 1);
  }
}

// ---------------- exclusive scan of 8 counts ----------------
__global__ void scan_kernel(const int* __restrict__ counts, int* __restrict__ offs,
                            int* __restrict__ fill) {
  if (threadIdx.x == 0) {
    int s = 0;
    for (int e = 0; e < NE; ++e) { offs[e] = s; s += counts[e]; }
    offs[NE] = s;
  }
  if (threadIdx.x < NE) fill[threadIdx.x] = 0;
}

// ---------------- scatter tokens into per-expert segments, cast x->fp16 ----------------
__global__ __launch_bounds__(256) void scatter_kernel(
    const float* __restrict__ x, const int* __restrict__ assign,
    const int* __restrict__ offs, int* __restrict__ fill,
    int* __restrict__ rowtok, _Float16* __restrict__ xg) {
  const int t = blockIdx.x;
  const int tid = threadIdx.x;
  __shared__ int spos;
  if (tid == 0) {
    int a = assign[t];
    int p = offs[a] + atomicAdd(&fill[a], 1);
    rowtok[p] = t;
    spos = p;
  }
  __syncthreads();
  int pos = spos;
  float4 v = ((const float4*)(x + (size_t)t * DD))[tid];
  union { ushort4 u; _Float16 h[4]; } cvt;
  cvt.h[0] = (_Float16)v.x; cvt.h[1] = (_Float16)v.y;
  cvt.h[2] = (_Float16)v.z; cvt.h[3] = (_Float16)v.w;
  ((ushort4*)(xg + (size_t)pos * DD))[tid] = cvt.u;
}

// ---------------- grouped GEMM: 128x128 tile, BK=32, 4 waves, mfma 16x16x32 f16 ----------------
// MODE 0: H = gelu_exact(A @ W1t^T + b1)  -> fp16
// MODE 1: out[tok] = (A @ W2t^T + b2) * wgt[tok] -> fp32, scattered by rowtok
template <int MODE>
__global__ __launch_bounds__(256) void gemm_kernel(
    const _Float16* __restrict__ A,    // [NT][DD] fp16 (segment-ordered)
    const _Float16* __restrict__ Wt,   // [NE][DD(n)][DD(k)] fp16
    const float* __restrict__ bias,    // [NE][DD]
    const int* __restrict__ offs,      // [NE+1]
    _Float16* __restrict__ Hout,       // MODE 0
    float* __restrict__ Fout,          // MODE 1
    const int* __restrict__ rowtok,    // MODE 1
    const float* __restrict__ wgt) {   // MODE 1
  const int e = blockIdx.z;
  const int seg_end = offs[e + 1];
  const int m0 = offs[e] + blockIdx.x * 128;
  if (m0 >= seg_end) return;
  const int n0 = blockIdx.y * 128;

  const int tid = threadIdx.x;
  const int lane = tid & 63;
  const int w = tid >> 6;
  const int wm = w >> 1, wn = w & 1;
  const int quad = lane >> 4;
  const int r15 = lane & 15;

  __shared__ alignas(16) _Float16 As[128 * 32];  // [row][4 chunks of 8, XOR-swizzled]
  __shared__ alignas(16) _Float16 Bs[128 * 32];  // [n-row][4 chunks of 8, XOR-swizzled]

  // staging source/dest: chunk s -> LDS offset s*16; logical chunk c = (s&3) ^ ((row>>1)&3)
  const int s0 = tid, s1 = tid + 256;
  const int ra0 = s0 >> 2, ra1 = s1 >> 2;
  const int c0 = (s0 & 3) ^ ((ra0 >> 1) & 3);
  const int c1 = (s1 & 3) ^ ((ra1 >> 1) & 3);
  int rowg0 = m0 + ra0; if (rowg0 > NT - 1) rowg0 = NT - 1;
  int rowg1 = m0 + ra1; if (rowg1 > NT - 1) rowg1 = NT - 1;
  const _Float16* gA0 = A + (size_t)rowg0 * DD + c0 * 8;
  const _Float16* gA1 = A + (size_t)rowg1 * DD + c1 * 8;
  const _Float16* We = Wt + (size_t)e * DD * DD;
  const _Float16* gB0 = We + (size_t)(n0 + ra0) * DD + c0 * 8;
  const _Float16* gB1 = We + (size_t)(n0 + ra1) * DD + c1 * 8;
  char* ldsA = (char*)As;
  char* ldsB = (char*)Bs;

  // fragment LDS read offsets (16B units), k-independent
  int aoff[4], boff[4];
#pragma unroll
  for (int i = 0; i < 4; ++i) {
    int m = wm * 64 + i * 16 + r15;
    aoff[i] = m * 4 + (quad ^ ((m >> 1) & 3));
    int n = wn * 64 + i * 16 + r15;
    boff[i] = n * 4 + (quad ^ ((n >> 1) & 3));
  }
  const half8* AsV = (const half8*)As;
  const half8* BsV = (const half8*)Bs;

  f32x4 acc[4][4];
  f32x4 zero4 = {0.f, 0.f, 0.f, 0.f};
#pragma unroll
  for (int mi = 0; mi < 4; ++mi)
#pragma unroll
    for (int ni = 0; ni < 4; ++ni) acc[mi][ni] = zero4;

#pragma unroll 1
  for (int k0 = 0; k0 < DD; k0 += 32) {
    __syncthreads();   // previous compute done before overwriting LDS
    GLDS16(gA0 + k0, ldsA + s0 * 16);
    GLDS16(gA1 + k0, ldsA + s1 * 16);
    GLDS16(gB0 + k0, ldsB + s0 * 16);
    GLDS16(gB1 + k0, ldsB + s1 * 16);
    __syncthreads();   // vmcnt(0) drain + barrier
    half8 a[4], b[4];
#pragma unroll
    for (int i = 0; i < 4; ++i) a[i] = AsV[aoff[i]];
#pragma unroll
    for (int i = 0; i < 4; ++i) b[i] = BsV[boff[i]];
#pragma unroll
    for (int mi = 0; mi < 4; ++mi)
#pragma unroll
      for (int ni = 0; ni < 4; ++ni)
        acc[mi][ni] = __builtin_amdgcn_mfma_f32_16x16x32_f16(a[mi], b[ni], acc[mi][ni], 0, 0, 0);
  }

  // epilogue. C/D layout: col = lane&15, row = quad*4 + reg
  const float* bptr = bias + (size_t)e * DD;
  if (MODE == 0) {
#pragma unroll
    for (int mi = 0; mi < 4; ++mi) {
      int rowb = m0 + wm * 64 + mi * 16 + quad * 4;
#pragma unroll
      for (int r = 0; r < 4; ++r) {
        int gpos = rowb + r;
        if (gpos < seg_end) {
#pragma unroll
          for (int ni = 0; ni < 4; ++ni) {
            int n = n0 + wn * 64 + ni * 16 + r15;
            float val = acc[mi][ni][r] + bptr[n];
            val = 0.5f * val * (1.0f + erff(val * 0.70710678118654752f));
            Hout[(size_t)gpos * DD + n] = (_Float16)val;
          }
        }
      }
    }
  } else {
#pragma unroll
    for (int mi = 0; mi < 4; ++mi) {
      int rowb = m0 + wm * 64 + mi * 16 + quad * 4;
#pragma unroll
      for (int r = 0; r < 4; ++r) {
        int gpos = rowb + r;
        if (gpos < seg_end) {
          int tok = rowtok[gpos];
          float wv = wgt[tok];
          float* orow = Fout + (size_t)tok * DD;
#pragma unroll
          for (int ni = 0; ni < 4; ++ni) {
            int n = n0 + wn * 64 + ni * 16 + r15;
            orow[n] = (acc[mi][ni][r] + bptr[n]) * wv;
          }
        }
      }
    }
  }
}

extern "C" void kernel_launch(void* const* d_in, const int* in_sizes, int n_in,
                              void* d_out, int out_size, void* d_ws, size_t ws_size,
                              hipStream_t stream) {
  const float* x  = (const float*)d_in[0];
  const float* Wg = (const float*)d_in[1];
  const float* bg = (const float*)d_in[2];
  const float* W1 = (const float*)d_in[3];
  const float* b1 = (const float*)d_in[4];
  const float* W2 = (const float*)d_in[5];
  const float* b2 = (const float*)d_in[6];
  float* out = (float*)d_out;

  // ws layout: 4 x 16MB fp16 buffers + small int/float arrays (~67.2 MB total)
  char* ws = (char*)d_ws;
  const size_t MB16 = (size_t)1 << 24;
  _Float16* W1t = (_Float16*)(ws + 0 * MB16);
  _Float16* W2t = (_Float16*)(ws + 1 * MB16);
  _Float16* xg  = (_Float16*)(ws + 2 * MB16);
  _Float16* H   = (_Float16*)(ws + 3 * MB16);
  int*   assign = (int*)(ws + 4 * MB16);
  int*   rowtok = assign + NT;
  float* wgt    = (float*)(rowtok + NT);
  int*   counts = (int*)(wgt + NT);
  int*   offs   = counts + NE;
  int*   fill   = offs + NE + 1;

  zero_kernel<<<1, 64, 0, stream>>>(counts);
  wcast_kernel<<<dim3(16, 16, 16), 256, 0, stream>>>(W1, W2, W1t, W2t);
  gate_kernel<<<NT, 256, 0, stream>>>(x, Wg, bg, assign, wgt, counts);
  scan_kernel<<<1, 64, 0, stream>>>(counts, offs, fill);
  scatter_kernel<<<NT, 256, 0, stream>>>(x, assign, offs, fill, rowtok, xg);
  gemm_kernel<0><<<dim3(64, 8, 8), 256, 0, stream>>>(xg, W1t, b1, offs, H, nullptr, nullptr, nullptr);
  gemm_kernel<1><<<dim3(64, 8, 8), 256, 0, stream>>>(H, W2t, b2, offs, nullptr, out, rowtok, wgt);
}

// Round 2
// 513.647 us; speedup vs baseline: 1.0735x; 1.0735x over previous
//
#include <hip/hip_runtime.h>
#include <cstdint>

#define NT 8192
#define DD 1024
#define NE 8
#define BK 64
#define NKIT (DD / BK)

typedef __attribute__((ext_vector_type(8))) _Float16 half8;
typedef __attribute__((ext_vector_type(4))) float f32x4;

__device__ __forceinline__ unsigned short f2h_bits(float f) {
  _Float16 h = (_Float16)f;
  return __builtin_bit_cast(unsigned short, h);
}

// async global->LDS, 16B per lane. LDS dest must be wave-uniform base + lane*16.
#define GLDS16(gp, lp) __builtin_amdgcn_global_load_lds( \
  (__attribute__((address_space(1))) void*)(uintptr_t)(gp), \
  (__attribute__((address_space(3))) void*)(uintptr_t)(lp), 16, 0, 0)

// ---------------- weight cast+transpose: fp32 [e][k][n] -> fp16 [e][n][k] ----------------
// block (0,0,0) also zeroes counts[8] and fill[8] (runs before gate/scatter in stream order)
__global__ __launch_bounds__(256) void wcast_kernel(
    const float* __restrict__ W1, const float* __restrict__ W2,
    _Float16* __restrict__ W1t, _Float16* __restrict__ W2t,
    int* __restrict__ counts, int* __restrict__ fill) {
  if (blockIdx.x == 0 && blockIdx.y == 0 && blockIdx.z == 0) {
    if (threadIdx.x < NE) counts[threadIdx.x] = 0;
    else if (threadIdx.x < 2 * NE) fill[threadIdx.x - NE] = 0;
  }
  __shared__ float tile[64][65];
  const int z = blockIdx.z;                // 0..15: [0,8)=W1, [8,16)=W2
  const float* W = (z < 8 ? W1 : W2) + (size_t)(z & 7) * (DD * DD);
  _Float16* Wt   = (z < 8 ? W1t : W2t) + (size_t)(z & 7) * (DD * DD);
  const int k0 = blockIdx.x * 64, n0 = blockIdx.y * 64;
  const int tid = threadIdx.x;
#pragma unroll
  for (int it = 0; it < 4; ++it) {
    int idx = it * 256 + tid;              // 0..1023
    int r = idx >> 4;                      // k-row 0..63
    int q = idx & 15;                      // float4 col
    float4 v = *(const float4*)(W + (size_t)(k0 + r) * DD + n0 + q * 4);
    tile[r][q * 4 + 0] = v.x; tile[r][q * 4 + 1] = v.y;
    tile[r][q * 4 + 2] = v.z; tile[r][q * 4 + 3] = v.w;
  }
  __syncthreads();
#pragma unroll
  for (int it = 0; it < 4; ++it) {
    int idx = it * 256 + tid;
    int n = idx >> 4;                      // out row (n) 0..63
    int q = idx & 15;                      // k 4-chunk
    ushort4 o;
    o.x = f2h_bits(tile[q * 4 + 0][n]);
    o.y = f2h_bits(tile[q * 4 + 1][n]);
    o.z = f2h_bits(tile[q * 4 + 2][n]);
    o.w = f2h_bits(tile[q * 4 + 3][n]);
    *(ushort4*)(Wt + (size_t)(n0 + n) * DD + k0 + q * 4) = o;
  }
}

// ---------------- gating: fp32 logits, softmax, argmax ----------------
__global__ __launch_bounds__(256) void gate_kernel(
    const float* __restrict__ x, const float* __restrict__ Wg, const float* __restrict__ bg,
    int* __restrict__ assign, float* __restrict__ wgt, int* __restrict__ counts) {
  const int t = blockIdx.x;
  const int tid = threadIdx.x;
  float4 xv = ((const float4*)(x + (size_t)t * DD))[tid];
  float xa[4] = {xv.x, xv.y, xv.z, xv.w};
  float p[NE];
#pragma unroll
  for (int e = 0; e < NE; ++e) p[e] = 0.f;
  const float* wr = Wg + (size_t)tid * 4 * NE;   // rows tid*4 .. +3
#pragma unroll
  for (int j = 0; j < 4; ++j) {
    float xs = xa[j];
#pragma unroll
    for (int e = 0; e < NE; ++e) p[e] += xs * wr[j * NE + e];
  }
#pragma unroll
  for (int e = 0; e < NE; ++e) {
    float v = p[e];
    for (int off = 32; off > 0; off >>= 1) v += __shfl_down(v, off, 64);
    p[e] = v;
  }
  __shared__ float red[4][NE];
  int lane = tid & 63, w = tid >> 6;
  if (lane == 0) {
#pragma unroll
    for (int e = 0; e < NE; ++e) red[w][e] = p[e];
  }
  __syncthreads();
  if (tid == 0) {
    float l[NE];
#pragma unroll
    for (int e = 0; e < NE; ++e) l[e] = red[0][e] + red[1][e] + red[2][e] + red[3][e] + bg[e];
    int a = 0; float best = l[0];
#pragma unroll
    for (int e = 1; e < NE; ++e) if (l[e] > best) { best = l[e]; a = e; }
    float s = 0.f;
#pragma unroll
    for (int e = 0; e < NE; ++e) s += expf(l[e] - best);
    assign[t] = a;
    wgt[t] = 1.0f / s;                     // = softmax prob of argmax expert
    atomicAdd(&counts[a], 1);
  }
}

// ---------------- scatter tokens into per-expert segments, cast x->fp16 ----------------
// computes the 8-expert exclusive prefix locally (no scan kernel)
__global__ __launch_bounds__(256) void scatter_kernel(
    const float* __restrict__ x, const int* __restrict__ assign,
    const int* __restrict__ counts, int* __restrict__ fill,
    int* __restrict__ rowtok, _Float16* __restrict__ xg) {
  const int t = blockIdx.x;
  const int tid = threadIdx.x;
  __shared__ int spos;
  if (tid == 0) {
    int a = assign[t];
    int off = 0;
    for (int e = 0; e < NE; ++e) off += (e < a) ? counts[e] : 0;
    int p = off + atomicAdd(&fill[a], 1);
    rowtok[p] = t;
    spos = p;
  }
  __syncthreads();
  int pos = spos;
  float4 v = ((const float4*)(x + (size_t)t * DD))[tid];
  union { ushort4 u; _Float16 h[4]; } cvt;
  cvt.h[0] = (_Float16)v.x; cvt.h[1] = (_Float16)v.y;
  cvt.h[2] = (_Float16)v.z; cvt.h[3] = (_Float16)v.w;
  ((ushort4*)(xg + (size_t)pos * DD))[tid] = cvt.u;
}

// ---------------- grouped GEMM: 128x128 tile, BK=64, double-buffered LDS pipeline ----------------
// MODE 0: H = gelu_exact(A @ W1t^T + b1)  -> fp16
// MODE 1: out[tok] = (A @ W2t^T + b2) * wgt[tok] -> fp32, scattered by rowtok
template <int MODE>
__global__ __launch_bounds__(256) void gemm_kernel(
    const _Float16* __restrict__ A,    // [NT][DD] fp16 (segment-ordered)
    const _Float16* __restrict__ Wt,   // [NE][DD(n)][DD(k)] fp16
    const float* __restrict__ bias,    // [NE][DD]
    const int* __restrict__ counts,    // [NE]
    _Float16* __restrict__ Hout,       // MODE 0
    float* __restrict__ Fout,          // MODE 1
    const int* __restrict__ rowtok,    // MODE 1
    const float* __restrict__ wgt) {   // MODE 1
  const int e = blockIdx.z;
  const int tid = threadIdx.x;

  __shared__ int offs_s[2];            // [seg_start, seg_end] for expert e
  if (tid == 0) {
    int s = 0, c = 0;
    for (int i = 0; i < NE; ++i) { int ci = counts[i]; if (i < e) s += ci; if (i == e) c = ci; }
    offs_s[0] = s; offs_s[1] = s + c;
  }
  __syncthreads();
  const int seg_end = offs_s[1];
  const int m0 = offs_s[0] + blockIdx.x * 128;
  if (m0 >= seg_end) return;           // block-uniform exit (after the only pre-loop barrier)
  const int n0 = blockIdx.y * 128;

  const int lane = tid & 63;
  const int w = tid >> 6;
  const int wm = w >> 1, wn = w & 1;
  const int quad = lane >> 4;
  const int r15 = lane & 15;

  // double-buffered tiles: [buf][row 0..127][8 chunks of 8 halves, XOR-swizzled by row&7]
  __shared__ alignas(16) _Float16 As[2 * 128 * BK];   // 32 KB
  __shared__ alignas(16) _Float16 Bs[2 * 128 * BK];   // 32 KB

  // staging addresses: instruction i stages slot = i*256 + tid (16B each);
  // slot -> row = slot>>3, stored-chunk sc = slot&7, logical chunk c = sc ^ (row&7)
  const _Float16* We = Wt + (size_t)e * DD * DD;
  const _Float16* gAp[4];
  const _Float16* gBp[4];
  int ldso[4];
#pragma unroll
  for (int i = 0; i < 4; ++i) {
    int slot = i * 256 + tid;
    int row = slot >> 3;
    int c = (slot & 7) ^ (row & 7);
    int rg = m0 + row; if (rg > NT - 1) rg = NT - 1;
    gAp[i] = A + (size_t)rg * DD + c * 8;
    gBp[i] = We + (size_t)(n0 + row) * DD + c * 8;
    ldso[i] = slot * 16;               // byte offset within buffer
  }

  // fragment LDS read offsets (half8 units within one buffer), k-chunk ks in {0,1}
  int aoff[2][4], boff[2][4];
#pragma unroll
  for (int ks = 0; ks < 2; ++ks)
#pragma unroll
    for (int i = 0; i < 4; ++i) {
      int m = wm * 64 + i * 16 + r15;
      aoff[ks][i] = m * 8 + ((ks * 4 + quad) ^ (m & 7));
      int n = wn * 64 + i * 16 + r15;
      boff[ks][i] = n * 8 + ((ks * 4 + quad) ^ (n & 7));
    }

  f32x4 acc[4][4];
  f32x4 zero4 = {0.f, 0.f, 0.f, 0.f};
#pragma unroll
  for (int mi = 0; mi < 4; ++mi)
#pragma unroll
    for (int ni = 0; ni < 4; ++ni) acc[mi][ni] = zero4;

  char* ldsA = (char*)As;
  char* ldsB = (char*)Bs;

#define STAGE(K0, BUF) do {                                          \
    char* la_ = ldsA + ((BUF) << 14);                                \
    char* lb_ = ldsB + ((BUF) << 14);                                \
    _Pragma("unroll") for (int i_ = 0; i_ < 4; ++i_)                 \
      GLDS16(gAp[i_] + (K0), la_ + ldso[i_]);                        \
    _Pragma("unroll") for (int i_ = 0; i_ < 4; ++i_)                 \
      GLDS16(gBp[i_] + (K0), lb_ + ldso[i_]);                        \
  } while (0)

  STAGE(0, 0);                          // prologue prefetch into buffer 0

#pragma unroll 1
  for (int kt = 0; kt < NKIT; ++kt) {
    const int buf = kt & 1;
    __syncthreads();                    // drains vmcnt -> buffer `buf` ready; syncs reads of buf^1
    if (kt + 1 < NKIT) STAGE((kt + 1) * BK, buf ^ 1);   // async prefetch overlaps compute below
    const half8* AsV = (const half8*)(ldsA + (buf << 14));
    const half8* BsV = (const half8*)(ldsB + (buf << 14));
#pragma unroll
    for (int ks = 0; ks < 2; ++ks) {
      half8 a[4], b[4];
#pragma unroll
      for (int i = 0; i < 4; ++i) a[i] = AsV[aoff[ks][i]];
#pragma unroll
      for (int i = 0; i < 4; ++i) b[i] = BsV[boff[ks][i]];
#pragma unroll
      for (int mi = 0; mi < 4; ++mi)
#pragma unroll
        for (int ni = 0; ni < 4; ++ni)
          acc[mi][ni] = __builtin_amdgcn_mfma_f32_16x16x32_f16(a[mi], b[ni], acc[mi][ni], 0, 0, 0);
    }
  }
#undef STAGE

  // epilogue. C/D layout: col = lane&15, row = quad*4 + reg
  const float* bptr = bias + (size_t)e * DD;
  if (MODE == 0) {
#pragma unroll
    for (int mi = 0; mi < 4; ++mi) {
      int rowb = m0 + wm * 64 + mi * 16 + quad * 4;
#pragma unroll
      for (int r = 0; r < 4; ++r) {
        int gpos = rowb + r;
        if (gpos < seg_end) {
#pragma unroll
          for (int ni = 0; ni < 4; ++ni) {
            int n = n0 + wn * 64 + ni * 16 + r15;
            float val = acc[mi][ni][r] + bptr[n];
            val = 0.5f * val * (1.0f + erff(val * 0.70710678118654752f));
            Hout[(size_t)gpos * DD + n] = (_Float16)val;
          }
        }
      }
    }
  } else {
#pragma unroll
    for (int mi = 0; mi < 4; ++mi) {
      int rowb = m0 + wm * 64 + mi * 16 + quad * 4;
#pragma unroll
      for (int r = 0; r < 4; ++r) {
        int gpos = rowb + r;
        if (gpos < seg_end) {
          int tok = rowtok[gpos];
          float wv = wgt[tok];
          float* orow = Fout + (size_t)tok * DD;
#pragma unroll
          for (int ni = 0; ni < 4; ++ni) {
            int n = n0 + wn * 64 + ni * 16 + r15;
            orow[n] = (acc[mi][ni][r] + bptr[n]) * wv;
          }
        }
      }
    }
  }
}

extern "C" void kernel_launch(void* const* d_in, const int* in_sizes, int n_in,
                              void* d_out, int out_size, void* d_ws, size_t ws_size,
                              hipStream_t stream) {
  const float* x  = (const float*)d_in[0];
  const float* Wg = (const float*)d_in[1];
  const float* bg = (const float*)d_in[2];
  const float* W1 = (const float*)d_in[3];
  const float* b1 = (const float*)d_in[4];
  const float* W2 = (const float*)d_in[5];
  const float* b2 = (const float*)d_in[6];
  float* out = (float*)d_out;

  // ws layout: 4 x 16MB fp16 buffers + small int/float arrays (~67.2 MB total)
  char* ws = (char*)d_ws;
  const size_t MB16 = (size_t)1 << 24;
  _Float16* W1t = (_Float16*)(ws + 0 * MB16);
  _Float16* W2t = (_Float16*)(ws + 1 * MB16);
  _Float16* xg  = (_Float16*)(ws + 2 * MB16);
  _Float16* H   = (_Float16*)(ws + 3 * MB16);
  int*   assign = (int*)(ws + 4 * MB16);
  int*   rowtok = assign + NT;
  float* wgt    = (float*)(rowtok + NT);
  int*   counts = (int*)(wgt + NT);
  int*   fill   = counts + NE;

  wcast_kernel<<<dim3(16, 16, 16), 256, 0, stream>>>(W1, W2, W1t, W2t, counts, fill);
  gate_kernel<<<NT, 256, 0, stream>>>(x, Wg, bg, assign, wgt, counts);
  scatter_kernel<<<NT, 256, 0, stream>>>(x, assign, counts, fill, rowtok, xg);
  gemm_kernel<0><<<dim3(64, 8, 8), 256, 0, stream>>>(xg, W1t, b1, counts, H, nullptr, nullptr, nullptr);
  gemm_kernel<1><<<dim3(64, 8, 8), 256, 0, stream>>>(H, W2t, b2, counts, nullptr, out, rowtok, wgt);
}

// Round 3
// 434.572 us; speedup vs baseline: 1.2689x; 1.1820x over previous
//
#include <hip/hip_runtime.h>
#include <cstdint>

#define NT 8192
#define DD 1024
#define NE 8
#define BK 64
#define NKIT (DD / BK)
#define MAXTILE 72

typedef __attribute__((ext_vector_type(8))) _Float16 half8;
typedef __attribute__((ext_vector_type(4))) float f32x4;

__device__ __forceinline__ unsigned short f2h_bits(float f) {
  _Float16 h = (_Float16)f;
  return __builtin_bit_cast(unsigned short, h);
}

// async global->LDS, 16B per lane. LDS dest must be wave-uniform base + lane*16.
#define GLDS16(gp, lp) __builtin_amdgcn_global_load_lds( \
  (__attribute__((address_space(1))) void*)(uintptr_t)(gp), \
  (__attribute__((address_space(3))) void*)(uintptr_t)(lp), 16, 0, 0)

// ---------------- weight cast+transpose: fp32 [e][k][n] -> fp16 [e][n][k] ----------------
// block (0,0,0) also zeroes counts[8] (runs before gate in stream order)
__global__ __launch_bounds__(256) void wcast_kernel(
    const float* __restrict__ W1, const float* __restrict__ W2,
    _Float16* __restrict__ W1t, _Float16* __restrict__ W2t,
    int* __restrict__ counts) {
  if (blockIdx.x == 0 && blockIdx.y == 0 && blockIdx.z == 0 && threadIdx.x < NE)
    counts[threadIdx.x] = 0;
  __shared__ float tile[64][65];
  const int z = blockIdx.z;                // 0..15: [0,8)=W1, [8,16)=W2
  const float* W = (z < 8 ? W1 : W2) + (size_t)(z & 7) * (DD * DD);
  _Float16* Wt   = (z < 8 ? W1t : W2t) + (size_t)(z & 7) * (DD * DD);
  const int k0 = blockIdx.x * 64, n0 = blockIdx.y * 64;
  const int tid = threadIdx.x;
#pragma unroll
  for (int it = 0; it < 4; ++it) {
    int idx = it * 256 + tid;              // 0..1023
    int r = idx >> 4;                      // k-row 0..63
    int q = idx & 15;                      // float4 col
    float4 v = *(const float4*)(W + (size_t)(k0 + r) * DD + n0 + q * 4);
    tile[r][q * 4 + 0] = v.x; tile[r][q * 4 + 1] = v.y;
    tile[r][q * 4 + 2] = v.z; tile[r][q * 4 + 3] = v.w;
  }
  __syncthreads();
#pragma unroll
  for (int it = 0; it < 4; ++it) {
    int idx = it * 256 + tid;
    int n = idx >> 4;                      // out row (n) 0..63
    int q = idx & 15;                      // k 4-chunk
    ushort4 o;
    o.x = f2h_bits(tile[q * 4 + 0][n]);
    o.y = f2h_bits(tile[q * 4 + 1][n]);
    o.z = f2h_bits(tile[q * 4 + 2][n]);
    o.w = f2h_bits(tile[q * 4 + 3][n]);
    *(ushort4*)(Wt + (size_t)(n0 + n) * DD + k0 + q * 4) = o;
  }
}

// ---------------- gating: fp32 logits, softmax, argmax ----------------
__global__ __launch_bounds__(256) void gate_kernel(
    const float* __restrict__ x, const float* __restrict__ Wg, const float* __restrict__ bg,
    int* __restrict__ assign, float* __restrict__ wgt, int* __restrict__ counts) {
  const int t = blockIdx.x;
  const int tid = threadIdx.x;
  float4 xv = ((const float4*)(x + (size_t)t * DD))[tid];
  float xa[4] = {xv.x, xv.y, xv.z, xv.w};
  float p[NE];
#pragma unroll
  for (int e = 0; e < NE; ++e) p[e] = 0.f;
  const float* wr = Wg + (size_t)tid * 4 * NE;   // rows tid*4 .. +3
#pragma unroll
  for (int j = 0; j < 4; ++j) {
    float xs = xa[j];
#pragma unroll
    for (int e = 0; e < NE; ++e) p[e] += xs * wr[j * NE + e];
  }
#pragma unroll
  for (int e = 0; e < NE; ++e) {
    float v = p[e];
    for (int off = 32; off > 0; off >>= 1) v += __shfl_down(v, off, 64);
    p[e] = v;
  }
  __shared__ float red[4][NE];
  int lane = tid & 63, w = tid >> 6;
  if (lane == 0) {
#pragma unroll
    for (int e = 0; e < NE; ++e) red[w][e] = p[e];
  }
  __syncthreads();
  if (tid == 0) {
    float l[NE];
#pragma unroll
    for (int e = 0; e < NE; ++e) l[e] = red[0][e] + red[1][e] + red[2][e] + red[3][e] + bg[e];
    int a = 0; float best = l[0];
#pragma unroll
    for (int e = 1; e < NE; ++e) if (l[e] > best) { best = l[e]; a = e; }
    float s = 0.f;
#pragma unroll
    for (int e = 0; e < NE; ++e) s += expf(l[e] - best);
    assign[t] = a;
    wgt[t] = 1.0f / s;                     // = softmax prob of argmax expert
    atomicAdd(&counts[a], 1);
  }
}

// ---------------- plan: offsets, tile table, zero fill ----------------
// plan[0] = ntiles; plan[1+i] = expert; plan[1+MAXTILE+i] = m0; plan[1+2*MAXTILE+i] = seg_end
__global__ void plan_kernel(const int* __restrict__ counts, int* __restrict__ offs,
                            int* __restrict__ fill, int* __restrict__ plan) {
  if (threadIdx.x == 0) {
    int s = 0, nt = 0;
    for (int e = 0; e < NE; ++e) {
      int c = counts[e];
      offs[e] = s;
      int t_cnt = (c + 127) >> 7;
      for (int t = 0; t < t_cnt; ++t) {
        plan[1 + nt] = e;
        plan[1 + MAXTILE + nt] = s + t * 128;
        plan[1 + 2 * MAXTILE + nt] = s + c;
        ++nt;
      }
      s += c;
    }
    offs[NE] = s;
    plan[0] = nt;
  }
  if (threadIdx.x < NE) fill[threadIdx.x] = 0;
}

// ---------------- scatter tokens into per-expert segments, cast x->fp16 ----------------
__global__ __launch_bounds__(256) void scatter_kernel(
    const float* __restrict__ x, const int* __restrict__ assign,
    const int* __restrict__ offs, int* __restrict__ fill,
    int* __restrict__ rowtok, _Float16* __restrict__ xg) {
  const int t = blockIdx.x;
  const int tid = threadIdx.x;
  __shared__ int spos;
  if (tid == 0) {
    int a = assign[t];
    int p = offs[a] + atomicAdd(&fill[a], 1);
    rowtok[p] = t;
    spos = p;
  }
  __syncthreads();
  int pos = spos;
  float4 v = ((const float4*)(x + (size_t)t * DD))[tid];
  union { ushort4 u; _Float16 h[4]; } cvt;
  cvt.h[0] = (_Float16)v.x; cvt.h[1] = (_Float16)v.y;
  cvt.h[2] = (_Float16)v.z; cvt.h[3] = (_Float16)v.w;
  ((ushort4*)(xg + (size_t)pos * DD))[tid] = cvt.u;
}

// ---------------- grouped GEMM: flat 1D work list, 128x128 tile, BK=64, dbuf pipeline ----------------
// work item w: tile = w>>3 (from plan table), nb = w&7 -> n0 = nb*128
// nb == w%8 -> XCD id, so each XCD re-reads the same 128-wide weight slice (L2-resident)
// MODE 0: H = gelu_exact(A @ W1t^T + b1)  -> fp16
// MODE 1: out[tok] = (A @ W2t^T + b2) * wgt[tok] -> fp32, scattered by rowtok
template <int MODE>
__global__ __launch_bounds__(256) void gemm_kernel(
    const _Float16* __restrict__ A,    // [NT][DD] fp16 (segment-ordered)
    const _Float16* __restrict__ Wt,   // [NE][DD(n)][DD(k)] fp16
    const float* __restrict__ bias,    // [NE][DD]
    const int* __restrict__ plan,      // tile table
    _Float16* __restrict__ Hout,       // MODE 0
    float* __restrict__ Fout,          // MODE 1
    const int* __restrict__ rowtok,    // MODE 1
    const float* __restrict__ wgt) {   // MODE 1
  const int wrk = blockIdx.x;
  const int tile = wrk >> 3;
  if (tile >= plan[0]) return;
  const int e = plan[1 + tile];
  const int m0 = plan[1 + MAXTILE + tile];
  const int seg_end = plan[1 + 2 * MAXTILE + tile];
  const int n0 = (wrk & 7) * 128;

  const int tid = threadIdx.x;
  const int lane = tid & 63;
  const int w = tid >> 6;
  const int wm = w >> 1, wn = w & 1;
  const int quad = lane >> 4;
  const int r15 = lane & 15;

  // double-buffered tiles: [buf][row 0..127][8 chunks of 8 halves, XOR-swizzled by row&7]
  __shared__ alignas(16) _Float16 As[2 * 128 * BK];   // 32 KB
  __shared__ alignas(16) _Float16 Bs[2 * 128 * BK];   // 32 KB

  // staging: instr i stages slot = i*256 + tid (16B each);
  // slot -> row = slot>>3, stored-chunk sc = slot&7, logical chunk c = sc ^ (row&7)
  const _Float16* We = Wt + (size_t)e * DD * DD;
  const _Float16* gAp[4];
  const _Float16* gBp[4];
  int ldso[4];
#pragma unroll
  for (int i = 0; i < 4; ++i) {
    int slot = i * 256 + tid;
    int row = slot >> 3;
    int c = (slot & 7) ^ (row & 7);
    int rg = m0 + row; if (rg > NT - 1) rg = NT - 1;
    gAp[i] = A + (size_t)rg * DD + c * 8;
    gBp[i] = We + (size_t)(n0 + row) * DD + c * 8;
    ldso[i] = slot * 16;               // byte offset within buffer
  }

  // fragment LDS read offsets (half8 units within one buffer), k-chunk ks in {0,1}
  int aoff[2][4], boff[2][4];
#pragma unroll
  for (int ks = 0; ks < 2; ++ks)
#pragma unroll
    for (int i = 0; i < 4; ++i) {
      int m = wm * 64 + i * 16 + r15;
      aoff[ks][i] = m * 8 + ((ks * 4 + quad) ^ (m & 7));
      int n = wn * 64 + i * 16 + r15;
      boff[ks][i] = n * 8 + ((ks * 4 + quad) ^ (n & 7));
    }

  f32x4 acc[4][4];
  f32x4 zero4 = {0.f, 0.f, 0.f, 0.f};
#pragma unroll
  for (int mi = 0; mi < 4; ++mi)
#pragma unroll
    for (int ni = 0; ni < 4; ++ni) acc[mi][ni] = zero4;

  char* ldsA = (char*)As;
  char* ldsB = (char*)Bs;

#define STAGE(K0, BUF) do {                                          \
    char* la_ = ldsA + ((BUF) << 14);                                \
    char* lb_ = ldsB + ((BUF) << 14);                                \
    _Pragma("unroll") for (int i_ = 0; i_ < 4; ++i_)                 \
      GLDS16(gAp[i_] + (K0), la_ + ldso[i_]);                        \
    _Pragma("unroll") for (int i_ = 0; i_ < 4; ++i_)                 \
      GLDS16(gBp[i_] + (K0), lb_ + ldso[i_]);                        \
  } while (0)

  STAGE(0, 0);                          // prologue prefetch into buffer 0

#pragma unroll 1
  for (int kt = 0; kt < NKIT; ++kt) {
    const int buf = kt & 1;
    __syncthreads();                    // drains vmcnt -> buffer `buf` ready; syncs reads of buf^1
    if (kt + 1 < NKIT) STAGE((kt + 1) * BK, buf ^ 1);   // async prefetch overlaps compute below
    const half8* AsV = (const half8*)(ldsA + (buf << 14));
    const half8* BsV = (const half8*)(ldsB + (buf << 14));
#pragma unroll
    for (int ks = 0; ks < 2; ++ks) {
      half8 a[4], b[4];
#pragma unroll
      for (int i = 0; i < 4; ++i) a[i] = AsV[aoff[ks][i]];
#pragma unroll
      for (int i = 0; i < 4; ++i) b[i] = BsV[boff[ks][i]];
#pragma unroll
      for (int mi = 0; mi < 4; ++mi)
#pragma unroll
        for (int ni = 0; ni < 4; ++ni)
          acc[mi][ni] = __builtin_amdgcn_mfma_f32_16x16x32_f16(a[mi], b[ni], acc[mi][ni], 0, 0, 0);
    }
  }
#undef STAGE

  // epilogue. C/D layout: col = lane&15, row = quad*4 + reg
  const float* bptr = bias + (size_t)e * DD;
  if (MODE == 0) {
#pragma unroll
    for (int mi = 0; mi < 4; ++mi) {
      int rowb = m0 + wm * 64 + mi * 16 + quad * 4;
#pragma unroll
      for (int r = 0; r < 4; ++r) {
        int gpos = rowb + r;
        if (gpos < seg_end) {
#pragma unroll
          for (int ni = 0; ni < 4; ++ni) {
            int n = n0 + wn * 64 + ni * 16 + r15;
            float val = acc[mi][ni][r] + bptr[n];
            val = 0.5f * val * (1.0f + erff(val * 0.70710678118654752f));
            Hout[(size_t)gpos * DD + n] = (_Float16)val;
          }
        }
      }
    }
  } else {
#pragma unroll
    for (int mi = 0; mi < 4; ++mi) {
      int rowb = m0 + wm * 64 + mi * 16 + quad * 4;
#pragma unroll
      for (int r = 0; r < 4; ++r) {
        int gpos = rowb + r;
        if (gpos < seg_end) {
          int tok = rowtok[gpos];
          float wv = wgt[tok];
          float* orow = Fout + (size_t)tok * DD;
#pragma unroll
          for (int ni = 0; ni < 4; ++ni) {
            int n = n0 + wn * 64 + ni * 16 + r15;
            orow[n] = (acc[mi][ni][r] + bptr[n]) * wv;
          }
        }
      }
    }
  }
}

extern "C" void kernel_launch(void* const* d_in, const int* in_sizes, int n_in,
                              void* d_out, int out_size, void* d_ws, size_t ws_size,
                              hipStream_t stream) {
  const float* x  = (const float*)d_in[0];
  const float* Wg = (const float*)d_in[1];
  const float* bg = (const float*)d_in[2];
  const float* W1 = (const float*)d_in[3];
  const float* b1 = (const float*)d_in[4];
  const float* W2 = (const float*)d_in[5];
  const float* b2 = (const float*)d_in[6];
  float* out = (float*)d_out;

  // ws layout: 4 x 16MB fp16 buffers + small int/float arrays (~67.2 MB total)
  char* ws = (char*)d_ws;
  const size_t MB16 = (size_t)1 << 24;
  _Float16* W1t = (_Float16*)(ws + 0 * MB16);
  _Float16* W2t = (_Float16*)(ws + 1 * MB16);
  _Float16* xg  = (_Float16*)(ws + 2 * MB16);
  _Float16* H   = (_Float16*)(ws + 3 * MB16);
  int*   assign = (int*)(ws + 4 * MB16);
  int*   rowtok = assign + NT;
  float* wgt    = (float*)(rowtok + NT);
  int*   counts = (int*)(wgt + NT);
  int*   offs   = counts + NE;         // [NE+1]
  int*   fill   = offs + NE + 1;
  int*   plan   = fill + NE;           // [1 + 3*MAXTILE]

  wcast_kernel<<<dim3(16, 16, 16), 256, 0, stream>>>(W1, W2, W1t, W2t, counts);
  gate_kernel<<<NT, 256, 0, stream>>>(x, Wg, bg, assign, wgt, counts);
  plan_kernel<<<1, 64, 0, stream>>>(counts, offs, fill, plan);
  scatter_kernel<<<NT, 256, 0, stream>>>(x, assign, offs, fill, rowtok, xg);
  gemm_kernel<0><<<MAXTILE * 8, 256, 0, stream>>>(xg, W1t, b1, plan, H, nullptr, nullptr, nullptr);
  gemm_kernel<1><<<MAXTILE * 8, 256, 0, stream>>>(H, W2t, b2, plan, nullptr, out, rowtok, wgt);
}

// Round 4
// 428.226 us; speedup vs baseline: 1.2877x; 1.0148x over previous
//
#include <hip/hip_runtime.h>
#include <cstdint>

#define NT 8192
#define DD 1024
#define NE 8
#define BK 64
#define NKIT (DD / BK)
#define MAXTILE 72

typedef __attribute__((ext_vector_type(8))) _Float16 half8;
typedef __attribute__((ext_vector_type(4))) float f32x4;

__device__ __forceinline__ unsigned short f2h_bits(float f) {
  _Float16 h = (_Float16)f;
  return __builtin_bit_cast(unsigned short, h);
}

// async global->LDS, 16B per lane. LDS dest must be wave-uniform base + lane*16.
#define GLDS16(gp, lp) __builtin_amdgcn_global_load_lds( \
  (__attribute__((address_space(1))) void*)(uintptr_t)(gp), \
  (__attribute__((address_space(3))) void*)(uintptr_t)(lp), 16, 0, 0)

// ---------------- weight cast+transpose: fp32 [e][k][n] -> fp16 [e][n][k] ----------------
// block (0,0,0) also zeroes counts[8] (runs before gate in stream order)
__global__ __launch_bounds__(256) void wcast_kernel(
    const float* __restrict__ W1, const float* __restrict__ W2,
    _Float16* __restrict__ W1t, _Float16* __restrict__ W2t,
    int* __restrict__ counts) {
  if (blockIdx.x == 0 && blockIdx.y == 0 && blockIdx.z == 0 && threadIdx.x < NE)
    counts[threadIdx.x] = 0;
  __shared__ float tile[64][65];
  const int z = blockIdx.z;                // 0..15: [0,8)=W1, [8,16)=W2
  const float* W = (z < 8 ? W1 : W2) + (size_t)(z & 7) * (DD * DD);
  _Float16* Wt   = (z < 8 ? W1t : W2t) + (size_t)(z & 7) * (DD * DD);
  const int k0 = blockIdx.x * 64, n0 = blockIdx.y * 64;
  const int tid = threadIdx.x;
#pragma unroll
  for (int it = 0; it < 4; ++it) {
    int idx = it * 256 + tid;              // 0..1023
    int r = idx >> 4;                      // k-row 0..63
    int q = idx & 15;                      // float4 col
    float4 v = *(const float4*)(W + (size_t)(k0 + r) * DD + n0 + q * 4);
    tile[r][q * 4 + 0] = v.x; tile[r][q * 4 + 1] = v.y;
    tile[r][q * 4 + 2] = v.z; tile[r][q * 4 + 3] = v.w;
  }
  __syncthreads();
#pragma unroll
  for (int it = 0; it < 4; ++it) {
    int idx = it * 256 + tid;
    int n = idx >> 4;                      // out row (n) 0..63
    int q = idx & 15;                      // k 4-chunk
    ushort4 o;
    o.x = f2h_bits(tile[q * 4 + 0][n]);
    o.y = f2h_bits(tile[q * 4 + 1][n]);
    o.z = f2h_bits(tile[q * 4 + 2][n]);
    o.w = f2h_bits(tile[q * 4 + 3][n]);
    *(ushort4*)(Wt + (size_t)(n0 + n) * DD + k0 + q * 4) = o;
  }
}

// ---------------- gating: Wg staged to LDS (e-major), one token per wave-pass ----------------
// 1024 blocks x 256 threads; block handles 8 tokens, each wave 2 tokens.
__global__ __launch_bounds__(256) void gate_kernel(
    const float* __restrict__ x, const float* __restrict__ Wg, const float* __restrict__ bg,
    int* __restrict__ assign, float* __restrict__ wgt, int* __restrict__ counts) {
  __shared__ float WgL[NE * DD];           // 32 KB, e-major: WgL[e*DD + k]
  const int tid = threadIdx.x;
  // stage Wg (global layout [k][e], 8 floats per k) coalesced, transpose into LDS
#pragma unroll
  for (int it = 0; it < 8; ++it) {
    int idx = it * 256 + tid;              // float4 index 0..2047
    float4 v = ((const float4*)Wg)[idx];
    int k = idx >> 1;
    int e0 = (idx & 1) * 4;
    WgL[(e0 + 0) * DD + k] = v.x;
    WgL[(e0 + 1) * DD + k] = v.y;
    WgL[(e0 + 2) * DD + k] = v.z;
    WgL[(e0 + 3) * DD + k] = v.w;
  }
  __syncthreads();
  const int lane = tid & 63, w = tid >> 6;
#pragma unroll
  for (int s = 0; s < 2; ++s) {
    const int t = blockIdx.x * 8 + w * 2 + s;
    const float4* xr = (const float4*)(x + (size_t)t * DD);
    float4 xv[4];
#pragma unroll
    for (int c = 0; c < 4; ++c) xv[c] = xr[lane + 64 * c];   // k = 4*lane + 256*c + [0..3]
    float p[NE];
#pragma unroll
    for (int e = 0; e < NE; ++e) {
      float acc = 0.f;
#pragma unroll
      for (int c = 0; c < 4; ++c) {
        float4 wv = *(const float4*)&WgL[e * DD + 4 * lane + 256 * c];
        acc += xv[c].x * wv.x + xv[c].y * wv.y + xv[c].z * wv.z + xv[c].w * wv.w;
      }
      p[e] = acc;
    }
#pragma unroll
    for (int e = 0; e < NE; ++e) {
      float v = p[e];
      for (int off = 32; off > 0; off >>= 1) v += __shfl_down(v, off, 64);
      p[e] = v;
    }
    if (lane == 0) {
      float l[NE];
#pragma unroll
      for (int e = 0; e < NE; ++e) l[e] = p[e] + bg[e];
      int a = 0; float best = l[0];
#pragma unroll
      for (int e = 1; e < NE; ++e) if (l[e] > best) { best = l[e]; a = e; }
      float sum = 0.f;
#pragma unroll
      for (int e = 0; e < NE; ++e) sum += expf(l[e] - best);
      assign[t] = a;
      wgt[t] = 1.0f / sum;                 // softmax prob of argmax expert
      atomicAdd(&counts[a], 1);
    }
  }
}

// ---------------- plan: offsets, tile table, zero fill ----------------
// plan[0] = ntiles; plan[1+i] = expert; plan[1+MAXTILE+i] = m0; plan[1+2*MAXTILE+i] = seg_end
__global__ void plan_kernel(const int* __restrict__ counts, int* __restrict__ offs,
                            int* __restrict__ fill, int* __restrict__ plan) {
  if (threadIdx.x == 0) {
    int s = 0, nt = 0;
    for (int e = 0; e < NE; ++e) {
      int c = counts[e];
      offs[e] = s;
      int t_cnt = (c + 127) >> 7;
      for (int t = 0; t < t_cnt; ++t) {
        plan[1 + nt] = e;
        plan[1 + MAXTILE + nt] = s + t * 128;
        plan[1 + 2 * MAXTILE + nt] = s + c;
        ++nt;
      }
      s += c;
    }
    offs[NE] = s;
    plan[0] = nt;
  }
  if (threadIdx.x < NE) fill[threadIdx.x] = 0;
}

// ---------------- scatter tokens into per-expert segments, cast x->fp16 ----------------
__global__ __launch_bounds__(256) void scatter_kernel(
    const float* __restrict__ x, const int* __restrict__ assign,
    const int* __restrict__ offs, int* __restrict__ fill,
    int* __restrict__ rowtok, _Float16* __restrict__ xg) {
  const int t = blockIdx.x;
  const int tid = threadIdx.x;
  __shared__ int spos;
  if (tid == 0) {
    int a = assign[t];
    int p = offs[a] + atomicAdd(&fill[a], 1);
    rowtok[p] = t;
    spos = p;
  }
  __syncthreads();
  int pos = spos;
  float4 v = ((const float4*)(x + (size_t)t * DD))[tid];
  union { ushort4 u; _Float16 h[4]; } cvt;
  cvt.h[0] = (_Float16)v.x; cvt.h[1] = (_Float16)v.y;
  cvt.h[2] = (_Float16)v.z; cvt.h[3] = (_Float16)v.w;
  ((ushort4*)(xg + (size_t)pos * DD))[tid] = cvt.u;
}

// ---------------- grouped GEMM: flat 1D work list, 128x128 tile, BK=64, dbuf pipeline ----------------
// work item w: tile = w>>3 (from plan table), nb = w&7 -> n0 = nb*128
// nb == w%8 -> XCD id, so each XCD re-reads the same 128-wide weight slice (L2-resident)
// MODE 0: H = gelu_exact(A @ W1t^T + b1)  -> fp16
// MODE 1: out[tok] = (A @ W2t^T + b2) * wgt[tok] -> fp32, scattered by rowtok
template <int MODE>
__global__ __launch_bounds__(256) void gemm_kernel(
    const _Float16* __restrict__ A,    // [NT][DD] fp16 (segment-ordered)
    const _Float16* __restrict__ Wt,   // [NE][DD(n)][DD(k)] fp16
    const float* __restrict__ bias,    // [NE][DD]
    const int* __restrict__ plan,      // tile table
    _Float16* __restrict__ Hout,       // MODE 0
    float* __restrict__ Fout,          // MODE 1
    const int* __restrict__ rowtok,    // MODE 1
    const float* __restrict__ wgt) {   // MODE 1
  const int wrk = blockIdx.x;
  const int tile = wrk >> 3;
  if (tile >= plan[0]) return;
  const int e = plan[1 + tile];
  const int m0 = plan[1 + MAXTILE + tile];
  const int seg_end = plan[1 + 2 * MAXTILE + tile];
  const int n0 = (wrk & 7) * 128;

  const int tid = threadIdx.x;
  const int lane = tid & 63;
  const int w = tid >> 6;
  const int wm = w >> 1, wn = w & 1;
  const int quad = lane >> 4;
  const int r15 = lane & 15;

  // double-buffered tiles: [buf][row 0..127][8 chunks of 8 halves, XOR-swizzled by row&7]
  __shared__ alignas(16) _Float16 As[2 * 128 * BK];   // 32 KB
  __shared__ alignas(16) _Float16 Bs[2 * 128 * BK];   // 32 KB

  // staging: instr i stages slot = i*256 + tid (16B each);
  // slot -> row = slot>>3, stored-chunk sc = slot&7, logical chunk c = sc ^ (row&7)
  const _Float16* We = Wt + (size_t)e * DD * DD;
  const _Float16* gAp[4];
  const _Float16* gBp[4];
  int ldso[4];
#pragma unroll
  for (int i = 0; i < 4; ++i) {
    int slot = i * 256 + tid;
    int row = slot >> 3;
    int c = (slot & 7) ^ (row & 7);
    int rg = m0 + row; if (rg > NT - 1) rg = NT - 1;
    gAp[i] = A + (size_t)rg * DD + c * 8;
    gBp[i] = We + (size_t)(n0 + row) * DD + c * 8;
    ldso[i] = slot * 16;               // byte offset within buffer
  }

  // fragment LDS read offsets (half8 units within one buffer), k-chunk ks in {0,1}
  int aoff[2][4], boff[2][4];
#pragma unroll
  for (int ks = 0; ks < 2; ++ks)
#pragma unroll
    for (int i = 0; i < 4; ++i) {
      int m = wm * 64 + i * 16 + r15;
      aoff[ks][i] = m * 8 + ((ks * 4 + quad) ^ (m & 7));
      int n = wn * 64 + i * 16 + r15;
      boff[ks][i] = n * 8 + ((ks * 4 + quad) ^ (n & 7));
    }

  f32x4 acc[4][4];
  f32x4 zero4 = {0.f, 0.f, 0.f, 0.f};
#pragma unroll
  for (int mi = 0; mi < 4; ++mi)
#pragma unroll
    for (int ni = 0; ni < 4; ++ni) acc[mi][ni] = zero4;

  char* ldsA = (char*)As;
  char* ldsB = (char*)Bs;

#define STAGE(K0, BUF) do {                                          \
    char* la_ = ldsA + ((BUF) << 14);                                \
    char* lb_ = ldsB + ((BUF) << 14);                                \
    _Pragma("unroll") for (int i_ = 0; i_ < 4; ++i_)                 \
      GLDS16(gAp[i_] + (K0), la_ + ldso[i_]);                        \
    _Pragma("unroll") for (int i_ = 0; i_ < 4; ++i_)                 \
      GLDS16(gBp[i_] + (K0), lb_ + ldso[i_]);                        \
  } while (0)

  STAGE(0, 0);                          // prologue prefetch into buffer 0

#pragma unroll 1
  for (int kt = 0; kt < NKIT; ++kt) {
    const int buf = kt & 1;
    __syncthreads();                    // drains vmcnt -> buffer `buf` ready; syncs reads of buf^1
    if (kt + 1 < NKIT) STAGE((kt + 1) * BK, buf ^ 1);   // async prefetch overlaps compute below
    const half8* AsV = (const half8*)(ldsA + (buf << 14));
    const half8* BsV = (const half8*)(ldsB + (buf << 14));
#pragma unroll
    for (int ks = 0; ks < 2; ++ks) {
      half8 a[4], b[4];
#pragma unroll
      for (int i = 0; i < 4; ++i) a[i] = AsV[aoff[ks][i]];
#pragma unroll
      for (int i = 0; i < 4; ++i) b[i] = BsV[boff[ks][i]];
#pragma unroll
      for (int mi = 0; mi < 4; ++mi)
#pragma unroll
        for (int ni = 0; ni < 4; ++ni)
          acc[mi][ni] = __builtin_amdgcn_mfma_f32_16x16x32_f16(a[mi], b[ni], acc[mi][ni], 0, 0, 0);
    }
  }
#undef STAGE

  // epilogue. C/D layout: col = lane&15, row = quad*4 + reg
  const float* bptr = bias + (size_t)e * DD;
  if (MODE == 0) {
#pragma unroll
    for (int mi = 0; mi < 4; ++mi) {
      int rowb = m0 + wm * 64 + mi * 16 + quad * 4;
#pragma unroll
      for (int r = 0; r < 4; ++r) {
        int gpos = rowb + r;
        if (gpos < seg_end) {
#pragma unroll
          for (int ni = 0; ni < 4; ++ni) {
            int n = n0 + wn * 64 + ni * 16 + r15;
            float val = acc[mi][ni][r] + bptr[n];
            val = 0.5f * val * (1.0f + erff(val * 0.70710678118654752f));
            Hout[(size_t)gpos * DD + n] = (_Float16)val;
          }
        }
      }
    }
  } else {
#pragma unroll
    for (int mi = 0; mi < 4; ++mi) {
      int rowb = m0 + wm * 64 + mi * 16 + quad * 4;
#pragma unroll
      for (int r = 0; r < 4; ++r) {
        int gpos = rowb + r;
        if (gpos < seg_end) {
          int tok = rowtok[gpos];
          float wv = wgt[tok];
          float* orow = Fout + (size_t)tok * DD;
#pragma unroll
          for (int ni = 0; ni < 4; ++ni) {
            int n = n0 + wn * 64 + ni * 16 + r15;
            orow[n] = (acc[mi][ni][r] + bptr[n]) * wv;
          }
        }
      }
    }
  }
}

extern "C" void kernel_launch(void* const* d_in, const int* in_sizes, int n_in,
                              void* d_out, int out_size, void* d_ws, size_t ws_size,
                              hipStream_t stream) {
  const float* x  = (const float*)d_in[0];
  const float* Wg = (const float*)d_in[1];
  const float* bg = (const float*)d_in[2];
  const float* W1 = (const float*)d_in[3];
  const float* b1 = (const float*)d_in[4];
  const float* W2 = (const float*)d_in[5];
  const float* b2 = (const float*)d_in[6];
  float* out = (float*)d_out;

  // ws layout: 4 x 16MB fp16 buffers + small int/float arrays (~67.2 MB total)
  char* ws = (char*)d_ws;
  const size_t MB16 = (size_t)1 << 24;
  _Float16* W1t = (_Float16*)(ws + 0 * MB16);
  _Float16* W2t = (_Float16*)(ws + 1 * MB16);
  _Float16* xg  = (_Float16*)(ws + 2 * MB16);
  _Float16* H   = (_Float16*)(ws + 3 * MB16);
  int*   assign = (int*)(ws + 4 * MB16);
  int*   rowtok = assign + NT;
  float* wgt    = (float*)(rowtok + NT);
  int*   counts = (int*)(wgt + NT);
  int*   offs   = counts + NE;         // [NE+1]
  int*   fill   = offs + NE + 1;
  int*   plan   = fill + NE;           // [1 + 3*MAXTILE]

  wcast_kernel<<<dim3(16, 16, 16), 256, 0, stream>>>(W1, W2, W1t, W2t, counts);
  gate_kernel<<<NT / 8, 256, 0, stream>>>(x, Wg, bg, assign, wgt, counts);
  plan_kernel<<<1, 64, 0, stream>>>(counts, offs, fill, plan);
  scatter_kernel<<<NT, 256, 0, stream>>>(x, assign, offs, fill, rowtok, xg);
  gemm_kernel<0><<<MAXTILE * 8, 256, 0, stream>>>(xg, W1t, b1, plan, H, nullptr, nullptr, nullptr);
  gemm_kernel<1><<<MAXTILE * 8, 256, 0, stream>>>(H, W2t, b2, plan, nullptr, out, rowtok, wgt);
}

// Round 5
// 259.211 us; speedup vs baseline: 2.1273x; 1.6520x over previous
//
#include <hip/hip_runtime.h>
#include <cstdint>

#define NT 8192
#define DD 1024
#define NE 8
#define BK 64
#define NKIT (DD / BK)
#define MAXTILE 72

typedef __attribute__((ext_vector_type(8))) _Float16 half8;
typedef __attribute__((ext_vector_type(4))) float f32x4;

__device__ __forceinline__ unsigned short f2h_bits(float f) {
  _Float16 h = (_Float16)f;
  return __builtin_bit_cast(unsigned short, h);
}

// async global->LDS, 16B per lane. LDS dest must be wave-uniform base + lane*16;
// the GLOBAL address is an ordinary per-lane VGPR address (indirection is fine).
#define GLDS16(gp, lp) __builtin_amdgcn_global_load_lds( \
  (__attribute__((address_space(1))) void*)(uintptr_t)(gp), \
  (__attribute__((address_space(3))) void*)(uintptr_t)(lp), 16, 0, 0)

// ---------------- weight cast+transpose: fp32 [e][k][n] -> fp16 [e][n][k] ----------------
__global__ __launch_bounds__(256) void wcast_kernel(
    const float* __restrict__ W1, const float* __restrict__ W2,
    _Float16* __restrict__ W1t, _Float16* __restrict__ W2t) {
  __shared__ float tile[64][65];
  const int z = blockIdx.z;                // 0..15: [0,8)=W1, [8,16)=W2
  const float* W = (z < 8 ? W1 : W2) + (size_t)(z & 7) * (DD * DD);
  _Float16* Wt   = (z < 8 ? W1t : W2t) + (size_t)(z & 7) * (DD * DD);
  const int k0 = blockIdx.x * 64, n0 = blockIdx.y * 64;
  const int tid = threadIdx.x;
#pragma unroll
  for (int it = 0; it < 4; ++it) {
    int idx = it * 256 + tid;              // 0..1023
    int r = idx >> 4;                      // k-row 0..63
    int q = idx & 15;                      // float4 col
    float4 v = *(const float4*)(W + (size_t)(k0 + r) * DD + n0 + q * 4);
    tile[r][q * 4 + 0] = v.x; tile[r][q * 4 + 1] = v.y;
    tile[r][q * 4 + 2] = v.z; tile[r][q * 4 + 3] = v.w;
  }
  __syncthreads();
#pragma unroll
  for (int it = 0; it < 4; ++it) {
    int idx = it * 256 + tid;
    int n = idx >> 4;                      // out row (n) 0..63
    int q = idx & 15;                      // k 4-chunk
    ushort4 o;
    o.x = f2h_bits(tile[q * 4 + 0][n]);
    o.y = f2h_bits(tile[q * 4 + 1][n]);
    o.z = f2h_bits(tile[q * 4 + 2][n]);
    o.w = f2h_bits(tile[q * 4 + 3][n]);
    *(ushort4*)(Wt + (size_t)(n0 + n) * DD + k0 + q * 4) = o;
  }
}

// ---------------- gating: Wg staged to LDS (e-major); also emits xh = fp16(x) ----------------
// 1024 blocks x 256 threads; block handles 8 tokens, each wave 2 tokens. NO atomics.
__global__ __launch_bounds__(256) void gate_kernel(
    const float* __restrict__ x, const float* __restrict__ Wg, const float* __restrict__ bg,
    int* __restrict__ assign, float* __restrict__ wgt, _Float16* __restrict__ xh) {
  __shared__ float WgL[NE * DD];           // 32 KB, e-major: WgL[e*DD + k]
  const int tid = threadIdx.x;
#pragma unroll
  for (int it = 0; it < 8; ++it) {
    int idx = it * 256 + tid;              // float4 index 0..2047
    float4 v = ((const float4*)Wg)[idx];
    int k = idx >> 1;
    int e0 = (idx & 1) * 4;
    WgL[(e0 + 0) * DD + k] = v.x;
    WgL[(e0 + 1) * DD + k] = v.y;
    WgL[(e0 + 2) * DD + k] = v.z;
    WgL[(e0 + 3) * DD + k] = v.w;
  }
  __syncthreads();
  const int lane = tid & 63, w = tid >> 6;
#pragma unroll
  for (int s = 0; s < 2; ++s) {
    const int t = blockIdx.x * 8 + w * 2 + s;
    const float4* xr = (const float4*)(x + (size_t)t * DD);
    float4 xv[4];
#pragma unroll
    for (int c = 0; c < 4; ++c) xv[c] = xr[lane + 64 * c];   // k = 4*(lane+64c) + [0..3]
    // fp16 copy of the row (token order)
    ushort4* xo = (ushort4*)(xh + (size_t)t * DD);
#pragma unroll
    for (int c = 0; c < 4; ++c) {
      union { ushort4 u; _Float16 h[4]; } cv;
      cv.h[0] = (_Float16)xv[c].x; cv.h[1] = (_Float16)xv[c].y;
      cv.h[2] = (_Float16)xv[c].z; cv.h[3] = (_Float16)xv[c].w;
      xo[lane + 64 * c] = cv.u;
    }
    float p[NE];
#pragma unroll
    for (int e = 0; e < NE; ++e) {
      float acc = 0.f;
#pragma unroll
      for (int c = 0; c < 4; ++c) {
        float4 wv = *(const float4*)&WgL[e * DD + 4 * lane + 256 * c];
        acc += xv[c].x * wv.x + xv[c].y * wv.y + xv[c].z * wv.z + xv[c].w * wv.w;
      }
      p[e] = acc;
    }
#pragma unroll
    for (int e = 0; e < NE; ++e) {
      float v = p[e];
      for (int off = 32; off > 0; off >>= 1) v += __shfl_down(v, off, 64);
      p[e] = v;
    }
    if (lane == 0) {
      float l[NE];
#pragma unroll
      for (int e = 0; e < NE; ++e) l[e] = p[e] + bg[e];
      int a = 0; float best = l[0];
#pragma unroll
      for (int e = 1; e < NE; ++e) if (l[e] > best) { best = l[e]; a = e; }
      float sum = 0.f;
#pragma unroll
      for (int e = 0; e < NE; ++e) sum += expf(l[e] - best);
      assign[t] = a;
      wgt[t] = 1.0f / sum;                 // softmax prob of argmax expert
    }
  }
}

// ---------------- sort: deterministic counting sort + tile plan, single block ----------------
// 1024 threads x 8 tokens each; LDS Hillis-Steele scan (e-major, conflict-free).
// rowtok[p] = token at segment position p; plan = tile table.
__global__ __launch_bounds__(1024) void sort_kernel(
    const int* __restrict__ assign, int* __restrict__ rowtok, int* __restrict__ plan) {
  __shared__ int sc[NE * 1024];            // 32 KB, e-major: sc[e*1024 + tid]
  const int tid = threadIdx.x;
  int a[8];
  int c[NE];
#pragma unroll
  for (int e = 0; e < NE; ++e) c[e] = 0;
#pragma unroll
  for (int j = 0; j < 8; ++j) { a[j] = assign[tid * 8 + j]; ++c[a[j]]; }
#pragma unroll
  for (int e = 0; e < NE; ++e) sc[e * 1024 + tid] = c[e];
  __syncthreads();
  for (int d = 1; d < 1024; d <<= 1) {
    int add[NE];
    if (tid >= d) {
#pragma unroll
      for (int e = 0; e < NE; ++e) add[e] = sc[e * 1024 + tid - d];
    }
    __syncthreads();
    if (tid >= d) {
#pragma unroll
      for (int e = 0; e < NE; ++e) sc[e * 1024 + tid] += add[e];
    }
    __syncthreads();
  }
  int tot[NE], incl[NE];
#pragma unroll
  for (int e = 0; e < NE; ++e) { tot[e] = sc[e * 1024 + 1023]; incl[e] = sc[e * 1024 + tid]; }
  int offs[NE];
  {
    int s = 0;
#pragma unroll
    for (int e = 0; e < NE; ++e) { offs[e] = s; s += tot[e]; }
  }
  int run[NE];
#pragma unroll
  for (int e = 0; e < NE; ++e) run[e] = offs[e] + incl[e] - c[e];
#pragma unroll
  for (int j = 0; j < 8; ++j) { int e = a[j]; rowtok[run[e]++] = tid * 8 + j; }
  if (tid == 0) {
    int nt = 0;
    for (int e = 0; e < NE; ++e) {
      int cc = tot[e], st = offs[e];
      int t_cnt = (cc + 127) >> 7;
      for (int t = 0; t < t_cnt; ++t) {
        plan[1 + nt] = e;
        plan[1 + MAXTILE + nt] = st + t * 128;
        plan[1 + 2 * MAXTILE + nt] = st + cc;
        ++nt;
      }
    }
    plan[0] = nt;
  }
}

// ---------------- grouped GEMM: flat 1D work list, 128x128 tile, BK=64, dbuf pipeline ----------------
// work item w: tile = w>>3 (plan table), nb = w&7 -> n0 = nb*128 (nb == XCD id -> L2-resident B slice)
// MODE 0: H[p] = gelu_exact(xh[rowtok[p]] @ W1t^T + b1)  -> fp16 (A staged via rowtok indirection)
// MODE 1: out[rowtok[p]] = (H[p] @ W2t^T + b2) * wgt      -> fp32 scatter
template <int MODE>
__global__ __launch_bounds__(256) void gemm_kernel(
    const _Float16* __restrict__ A,    // MODE0: xh (token order); MODE1: H (segment order)
    const _Float16* __restrict__ Wt,   // [NE][DD(n)][DD(k)] fp16
    const float* __restrict__ bias,    // [NE][DD]
    const int* __restrict__ plan,      // tile table
    _Float16* __restrict__ Hout,       // MODE 0
    float* __restrict__ Fout,          // MODE 1
    const int* __restrict__ rowtok,
    const float* __restrict__ wgt) {   // MODE 1
  const int wrk = blockIdx.x;
  const int tile = wrk >> 3;
  if (tile >= plan[0]) return;
  const int e = plan[1 + tile];
  const int m0 = plan[1 + MAXTILE + tile];
  const int seg_end = plan[1 + 2 * MAXTILE + tile];
  const int n0 = (wrk & 7) * 128;

  const int tid = threadIdx.x;
  const int lane = tid & 63;
  const int w = tid >> 6;
  const int wm = w >> 1, wn = w & 1;
  const int quad = lane >> 4;
  const int r15 = lane & 15;

  // double-buffered tiles: [buf][row 0..127][8 chunks of 8 halves, XOR-swizzled by row&7]
  __shared__ alignas(16) _Float16 As[2 * 128 * BK];   // 32 KB
  __shared__ alignas(16) _Float16 Bs[2 * 128 * BK];   // 32 KB

  // staging: instr i stages slot = i*256 + tid (16B each);
  // slot -> row = slot>>3, stored-chunk sc = slot&7, logical chunk c = sc ^ (row&7)
  const _Float16* We = Wt + (size_t)e * DD * DD;
  const _Float16* gAp[4];
  const _Float16* gBp[4];
  int ldso[4];
#pragma unroll
  for (int i = 0; i < 4; ++i) {
    int slot = i * 256 + tid;
    int row = slot >> 3;
    int c = (slot & 7) ^ (row & 7);
    int rg = m0 + row; if (rg > NT - 1) rg = NT - 1;
    int arow = (MODE == 0) ? rowtok[rg] : rg;   // A-row indirection for layer 1
    gAp[i] = A + (size_t)arow * DD + c * 8;
    gBp[i] = We + (size_t)(n0 + row) * DD + c * 8;
    ldso[i] = slot * 16;               // byte offset within buffer
  }

  // fragment LDS read offsets (half8 units within one buffer), k-chunk ks in {0,1}
  int aoff[2][4], boff[2][4];
#pragma unroll
  for (int ks = 0; ks < 2; ++ks)
#pragma unroll
    for (int i = 0; i < 4; ++i) {
      int m = wm * 64 + i * 16 + r15;
      aoff[ks][i] = m * 8 + ((ks * 4 + quad) ^ (m & 7));
      int n = wn * 64 + i * 16 + r15;
      boff[ks][i] = n * 8 + ((ks * 4 + quad) ^ (n & 7));
    }

  f32x4 acc[4][4];
  f32x4 zero4 = {0.f, 0.f, 0.f, 0.f};
#pragma unroll
  for (int mi = 0; mi < 4; ++mi)
#pragma unroll
    for (int ni = 0; ni < 4; ++ni) acc[mi][ni] = zero4;

  char* ldsA = (char*)As;
  char* ldsB = (char*)Bs;

#define STAGE(K0, BUF) do {                                          \
    char* la_ = ldsA + ((BUF) << 14);                                \
    char* lb_ = ldsB + ((BUF) << 14);                                \
    _Pragma("unroll") for (int i_ = 0; i_ < 4; ++i_)                 \
      GLDS16(gAp[i_] + (K0), la_ + ldso[i_]);                        \
    _Pragma("unroll") for (int i_ = 0; i_ < 4; ++i_)                 \
      GLDS16(gBp[i_] + (K0), lb_ + ldso[i_]);                        \
  } while (0)

  STAGE(0, 0);                          // prologue prefetch into buffer 0

#pragma unroll 1
  for (int kt = 0; kt < NKIT; ++kt) {
    const int buf = kt & 1;
    __syncthreads();                    // drains vmcnt -> buffer `buf` ready; syncs reads of buf^1
    if (kt + 1 < NKIT) STAGE((kt + 1) * BK, buf ^ 1);   // async prefetch overlaps compute below
    const half8* AsV = (const half8*)(ldsA + (buf << 14));
    const half8* BsV = (const half8*)(ldsB + (buf << 14));
#pragma unroll
    for (int ks = 0; ks < 2; ++ks) {
      half8 a[4], b[4];
#pragma unroll
      for (int i = 0; i < 4; ++i) a[i] = AsV[aoff[ks][i]];
#pragma unroll
      for (int i = 0; i < 4; ++i) b[i] = BsV[boff[ks][i]];
#pragma unroll
      for (int mi = 0; mi < 4; ++mi)
#pragma unroll
        for (int ni = 0; ni < 4; ++ni)
          acc[mi][ni] = __builtin_amdgcn_mfma_f32_16x16x32_f16(a[mi], b[ni], acc[mi][ni], 0, 0, 0);
    }
  }
#undef STAGE

  // epilogue. C/D layout: col = lane&15, row = quad*4 + reg
  const float* bptr = bias + (size_t)e * DD;
  if (MODE == 0) {
#pragma unroll
    for (int mi = 0; mi < 4; ++mi) {
      int rowb = m0 + wm * 64 + mi * 16 + quad * 4;
#pragma unroll
      for (int r = 0; r < 4; ++r) {
        int gpos = rowb + r;
        if (gpos < seg_end) {
#pragma unroll
          for (int ni = 0; ni < 4; ++ni) {
            int n = n0 + wn * 64 + ni * 16 + r15;
            float val = acc[mi][ni][r] + bptr[n];
            val = 0.5f * val * (1.0f + erff(val * 0.70710678118654752f));
            Hout[(size_t)gpos * DD + n] = (_Float16)val;
          }
        }
      }
    }
  } else {
#pragma unroll
    for (int mi = 0; mi < 4; ++mi) {
      int rowb = m0 + wm * 64 + mi * 16 + quad * 4;
#pragma unroll
      for (int r = 0; r < 4; ++r) {
        int gpos = rowb + r;
        if (gpos < seg_end) {
          int tok = rowtok[gpos];
          float wv = wgt[tok];
          float* orow = Fout + (size_t)tok * DD;
#pragma unroll
          for (int ni = 0; ni < 4; ++ni) {
            int n = n0 + wn * 64 + ni * 16 + r15;
            orow[n] = (acc[mi][ni][r] + bptr[n]) * wv;
          }
        }
      }
    }
  }
}

extern "C" void kernel_launch(void* const* d_in, const int* in_sizes, int n_in,
                              void* d_out, int out_size, void* d_ws, size_t ws_size,
                              hipStream_t stream) {
  const float* x  = (const float*)d_in[0];
  const float* Wg = (const float*)d_in[1];
  const float* bg = (const float*)d_in[2];
  const float* W1 = (const float*)d_in[3];
  const float* b1 = (const float*)d_in[4];
  const float* W2 = (const float*)d_in[5];
  const float* b2 = (const float*)d_in[6];
  float* out = (float*)d_out;

  // ws layout: 4 x 16MB fp16 buffers + small int/float arrays (~67.2 MB total)
  char* ws = (char*)d_ws;
  const size_t MB16 = (size_t)1 << 24;
  _Float16* W1t = (_Float16*)(ws + 0 * MB16);
  _Float16* W2t = (_Float16*)(ws + 1 * MB16);
  _Float16* xh  = (_Float16*)(ws + 2 * MB16);
  _Float16* H   = (_Float16*)(ws + 3 * MB16);
  int*   assign = (int*)(ws + 4 * MB16);
  int*   rowtok = assign + NT;
  float* wgt    = (float*)(rowtok + NT);
  int*   plan   = (int*)(wgt + NT);    // [1 + 3*MAXTILE]

  wcast_kernel<<<dim3(16, 16, 16), 256, 0, stream>>>(W1, W2, W1t, W2t);
  gate_kernel<<<NT / 8, 256, 0, stream>>>(x, Wg, bg, assign, wgt, xh);
  sort_kernel<<<1, 1024, 0, stream>>>(assign, rowtok, plan);
  gemm_kernel<0><<<MAXTILE * 8, 256, 0, stream>>>(xh, W1t, b1, plan, H, nullptr, rowtok, nullptr);
  gemm_kernel<1><<<MAXTILE * 8, 256, 0, stream>>>(H, W2t, b2, plan, nullptr, out, rowtok, wgt);
}